// Round 1
// baseline (792.976 us; speedup 1.0000x reference)
//
#include <hip/hip_runtime.h>
#include <hip/hip_bf16.h>

// RBF-kernel attention, MI355X.  B=8, Q=K=4096, D=256, d=64.
// Outputs (concat fp32): out [8,4096,64] then attn [8,4096,4096].
// Strategy: f16 MFMA (16x16x32) everywhere; two-pass (rowsum, then
// normalize+write+PV) recompute to avoid re-reading the 536MB attn.

typedef _Float16 HALF;
typedef HALF half8 __attribute__((ext_vector_type(8)));
typedef float f32x4 __attribute__((ext_vector_type(4)));

#define MFMA16(a, b, c) __builtin_amdgcn_mfma_f32_16x16x32_f16((a), (b), (c), 0, 0, 0)

union Cv4 { HALF h[4]; uint2 u; };
union Cv8 { HALF h[8]; uint4 u; };

// ---------------- kernel 0: W transposes -> f16 ----------------
// wt[t][n][k] = W_t[k][n]  (t: 0=Wq,1=Wk,2=Wv), wto[n][k] = Wo[k][n]
__global__ __launch_bounds__(256) void k_prep(const float* __restrict__ Wq,
                                              const float* __restrict__ Wk,
                                              const float* __restrict__ Wv,
                                              const float* __restrict__ Wo,
                                              HALF* __restrict__ wt,
                                              HALF* __restrict__ wto) {
    int gid = blockIdx.x * 256 + threadIdx.x;   // 208*256 = 53248 exact
    if (gid < 49152) {
        int t = gid >> 14;
        int rem = gid & 16383;
        int n = rem >> 8, k = rem & 255;
        const float* W = (t == 0) ? Wq : ((t == 1) ? Wk : Wv);
        wt[gid] = (HALF)W[k * 64 + n];
    } else {
        int rem = gid - 49152;
        int n = rem >> 6, k = rem & 63;
        wto[rem] = (HALF)Wo[k * 64 + n];
    }
}

// ---------------- kernel 1: projections ----------------
// grid = 3*8*64 blocks of 256.  Each block: 64 rows x 64 cols, K=256.
// Emits q_h/k_h row-major f16, v transposed vt[b][dv][key] f16,
// q2/k2 fp32 row-norms (bias included).
__global__ __launch_bounds__(256) void k_proj(const float* __restrict__ qs,
                                              const float* __restrict__ ks,
                                              const float* __restrict__ vs,
                                              const float* __restrict__ bq,
                                              const float* __restrict__ bk,
                                              const float* __restrict__ bv,
                                              const HALF* __restrict__ wt,
                                              HALF* __restrict__ qh,
                                              HALF* __restrict__ kh,
                                              HALF* __restrict__ vth,
                                              float* __restrict__ q2w,
                                              float* __restrict__ k2w) {
    int bid = blockIdx.x;
    int t = bid >> 9;           // which projection
    int rem = bid & 511;
    int b = rem & 7, rt = rem >> 3;
    int m0 = rt * 64;
    const float* X    = (t == 0) ? qs : ((t == 1) ? ks : vs);
    const float* bias = (t == 0) ? bq : ((t == 1) ? bk : bv);

    __shared__ char smem[67584];
    HALF (*sW)[264]  = (HALF(*)[264])smem;             // 33792 B
    HALF (*sX)[264]  = (HALF(*)[264])(smem + 33792);   // 33792 B
    float (*sOut)[68] = (float(*)[68])(smem + 33792);  // overlaps sX (17408 B)

    int tid = threadIdx.x;
    int w = tid >> 6, lane = tid & 63, ln = lane & 15, quad = lane >> 4;

    const HALF* wsrc = wt + t * 16384;
#pragma unroll
    for (int s = 0; s < 8; ++s) {                      // stage W^T tile (32KB)
        int flat = (s * 256 + tid) * 8;
        int r = flat >> 8, c = flat & 255;
        *(uint4*)&sW[r][c] = *(const uint4*)(wsrc + flat);
    }
    const float* xbase = X + ((size_t)(b * 4096 + m0)) * 256;
#pragma unroll
    for (int s = 0; s < 16; ++s) {                     // stage X tile fp32->f16
        int flat = (s * 256 + tid) * 4;
        int r = flat >> 8, c = flat & 255;
        float4 xv = *(const float4*)(xbase + flat);
        Cv4 cv; cv.h[0] = (HALF)xv.x; cv.h[1] = (HALF)xv.y;
        cv.h[2] = (HALF)xv.z; cv.h[3] = (HALF)xv.w;
        *(uint2*)&sX[r][c] = cv.u;
    }
    __syncthreads();

    f32x4 zero4 = {0.f, 0.f, 0.f, 0.f};
    f32x4 acc[4] = {zero4, zero4, zero4, zero4};
#pragma unroll
    for (int kb = 0; kb < 8; ++kb) {
        half8 a = *(half8*)&sX[w * 16 + ln][kb * 32 + quad * 8];
#pragma unroll
        for (int t4 = 0; t4 < 4; ++t4) {
            half8 bf = *(half8*)&sW[t4 * 16 + ln][kb * 32 + quad * 8];
            acc[t4] = MFMA16(a, bf, acc[t4]);
        }
    }
    __syncthreads();   // done reading sX; reuse as sOut

    float bias_v[4];
#pragma unroll
    for (int t4 = 0; t4 < 4; ++t4) bias_v[t4] = bias[t4 * 16 + ln];

    float rsq[4] = {0.f, 0.f, 0.f, 0.f};
#pragma unroll
    for (int t4 = 0; t4 < 4; ++t4) {
#pragma unroll
        for (int r = 0; r < 4; ++r) {
            float v = acc[t4][r] + bias_v[t4];
            rsq[r] += v * v;
            sOut[w * 16 + quad * 4 + r][t4 * 16 + ln] = v;
        }
    }
    if (t < 2) {
        float* dst2 = (t == 0) ? q2w : k2w;
#pragma unroll
        for (int r = 0; r < 4; ++r) {
            float v = rsq[r];
#pragma unroll
            for (int off = 1; off < 16; off <<= 1) v += __shfl_xor(v, off);
            if (ln == 0) dst2[b * 4096 + m0 + w * 16 + quad * 4 + r] = v;
        }
    }
    __syncthreads();

    if (t < 2) {
        HALF* dst = ((t == 0) ? qh : kh) + ((size_t)(b * 4096 + m0)) * 64;
#pragma unroll
        for (int s = 0; s < 4; ++s) {
            int flat = (s * 256 + tid) * 4;
            int r = flat >> 6, c = flat & 63;
            float4 v = *(float4*)&sOut[r][c];
            Cv4 cv; cv.h[0] = (HALF)v.x; cv.h[1] = (HALF)v.y;
            cv.h[2] = (HALF)v.z; cv.h[3] = (HALF)v.w;
            *(uint2*)(dst + flat) = cv.u;
        }
    } else {
        // v stored transposed: vt[b][dv][key]
        HALF* dst = vth + (size_t)b * 64 * 4096 + m0;
#pragma unroll
        for (int s = 0; s < 2; ++s) {
            int dv = s * 32 + (tid >> 3);
            int kc = (tid & 7) * 8;
            Cv8 cv;
#pragma unroll
            for (int i = 0; i < 8; ++i) cv.h[i] = (HALF)sOut[kc + i][dv];
            *(uint4*)(dst + (size_t)dv * 4096 + kc) = cv.u;
        }
    }
}

// ---------------- kernel 2: two-pass RBF attention ----------------
// grid = 512 blocks (b = bid&7 pins batch->XCD for k/v L2 residence).
// Each block: 64 Q-rows. Pass A: rowsums. Pass B: recompute, normalize,
// write attn (LDS->float4 rows), PV into ctx accumulators.
__global__ __launch_bounds__(256) void k_attn(const HALF* __restrict__ qh,
                                              const HALF* __restrict__ kh,
                                              const HALF* __restrict__ vth,
                                              const float* __restrict__ q2w,
                                              const float* __restrict__ k2w,
                                              const int* __restrict__ vlen,
                                              float* __restrict__ attn_out,
                                              float* __restrict__ ctx_out) {
    int bid = blockIdx.x;
    int b = bid & 7, qt = bid >> 3;
    int m0 = qt * 64;
    int tid = threadIdx.x;
    int w = tid >> 6, lane = tid & 63, ln = lane & 15, quad = lane >> 4;
    int valid = vlen[b];

    __shared__ char smem[36608];
    HALF (*sK)[72]  = (HALF(*)[72])smem;               //  9216 B
    HALF (*sVt)[72] = (HALF(*)[72])(smem + 9216);      //  9216 B
    float (*sS)[68] = (float(*)[68])(smem + 18432);    // 17408 B
    HALF (*sQ)[72]  = (HALF(*)[72])(smem + 18432);     // overlaps sS
    float* sQ2 = (float*)(smem + 35840);
    float* sK2 = sQ2 + 64;
    float* sRS = sK2 + 64;

    // stage q tile + q2
    const HALF* qbase = qh + ((size_t)(b * 4096 + m0)) * 64;
#pragma unroll
    for (int s = 0; s < 2; ++s) {
        int flat = (s * 256 + tid) * 8;
        *(uint4*)&sQ[flat >> 6][flat & 63] = *(const uint4*)(qbase + flat);
    }
    if (tid < 64) sQ2[tid] = q2w[b * 4096 + m0 + tid];
    __syncthreads();

    half8 qa[2];
    {
        int row = w * 16 + ln, k0 = quad * 8;
        qa[0] = *(half8*)&sQ[row][k0];
        qa[1] = *(half8*)&sQ[row][32 + k0];
    }
    __syncthreads();   // sQ region now free (becomes sS in pass B)

    int nvt = (valid + 63) >> 6;
    const HALF* kbb = kh + (size_t)b * 4096 * 64;
    const HALF* vtb = vth + (size_t)b * 64 * 4096;

    float rs[4] = {0.f, 0.f, 0.f, 0.f};

    // ---- pass A: rowsums over valid tiles ----
    for (int nt = 0; nt < nvt; ++nt) {
        int n0 = nt * 64;
#pragma unroll
        for (int s = 0; s < 2; ++s) {
            int flat = (s * 256 + tid) * 8;
            *(uint4*)&sK[flat >> 6][flat & 63] = *(const uint4*)(kbb + (size_t)n0 * 64 + flat);
        }
        if (tid < 64) sK2[tid] = k2w[b * 4096 + n0 + tid];
        __syncthreads();
#pragma unroll
        for (int t4 = 0; t4 < 4; ++t4) {
            f32x4 acc = {0.f, 0.f, 0.f, 0.f};
            half8 b0 = *(half8*)&sK[t4 * 16 + ln][quad * 8];
            half8 b1 = *(half8*)&sK[t4 * 16 + ln][32 + quad * 8];
            acc = MFMA16(qa[0], b0, acc);
            acc = MFMA16(qa[1], b1, acc);
            int col = t4 * 16 + ln;
            float k2v = sK2[col];
            bool ok = (n0 + col) < valid;
#pragma unroll
            for (int r = 0; r < 4; ++r) {
                int row = w * 16 + quad * 4 + r;
                float dsq = fmaxf(sQ2[row] + k2v - 2.f * acc[r], 0.f);
                float e = ok ? __expf(-0.125f * dsq) : 0.f;
                rs[r] += e;
            }
        }
        __syncthreads();
    }

    // rowsum reduce across the 16 lanes of each quad
#pragma unroll
    for (int r = 0; r < 4; ++r) {
        float v = rs[r];
#pragma unroll
        for (int off = 1; off < 16; off <<= 1) v += __shfl_xor(v, off);
        rs[r] = v;
    }
    if (ln == 0) {
#pragma unroll
        for (int r = 0; r < 4; ++r) sRS[w * 16 + quad * 4 + r] = rs[r];
    }
    __syncthreads();
    if (tid < 64) sRS[tid] = 1.0f / sRS[tid];
    __syncthreads();
    float inv_r[4];
#pragma unroll
    for (int r = 0; r < 4; ++r) inv_r[r] = sRS[w * 16 + quad * 4 + r];

    f32x4 cz = {0.f, 0.f, 0.f, 0.f};
    f32x4 cacc[4] = {cz, cz, cz, cz};
    float* attn_base = attn_out + ((size_t)(b * 4096 + m0)) * 4096;

    // ---- pass B: recompute, normalize, write, PV ----
    for (int nt = 0; nt < nvt; ++nt) {
        int n0 = nt * 64;
#pragma unroll
        for (int s = 0; s < 2; ++s) {
            int flat = (s * 256 + tid) * 8;
            *(uint4*)&sK[flat >> 6][flat & 63] = *(const uint4*)(kbb + (size_t)n0 * 64 + flat);
        }
#pragma unroll
        for (int s = 0; s < 2; ++s) {
            int flat = (s * 256 + tid) * 8;
            int dv = flat >> 6, c = flat & 63;
            *(uint4*)&sVt[dv][c] = *(const uint4*)(vtb + (size_t)dv * 4096 + n0 + c);
        }
        if (tid < 64) sK2[tid] = k2w[b * 4096 + n0 + tid];
        __syncthreads();
#pragma unroll
        for (int t4 = 0; t4 < 4; ++t4) {
            f32x4 acc = {0.f, 0.f, 0.f, 0.f};
            half8 b0 = *(half8*)&sK[t4 * 16 + ln][quad * 8];
            half8 b1 = *(half8*)&sK[t4 * 16 + ln][32 + quad * 8];
            acc = MFMA16(qa[0], b0, acc);
            acc = MFMA16(qa[1], b1, acc);
            int col = t4 * 16 + ln;
            float k2v = sK2[col];
            bool ok = (n0 + col) < valid;
#pragma unroll
            for (int r = 0; r < 4; ++r) {
                int row = w * 16 + quad * 4 + r;
                float dsq = fmaxf(sQ2[row] + k2v - 2.f * acc[r], 0.f);
                float e = ok ? __expf(-0.125f * dsq) : 0.f;
                sS[row][col] = e * inv_r[r];
            }
        }
        __syncthreads();
        // coalesced global write of the normalized tile (256B per row)
#pragma unroll
        for (int s = 0; s < 4; ++s) {
            int row = s * 16 + (tid >> 4);
            int col = (tid & 15) * 4;
            *(float4*)(attn_base + (size_t)row * 4096 + n0 + col) = *(float4*)&sS[row][col];
        }
        // PV with the normalized probs
#pragma unroll
        for (int ks2 = 0; ks2 < 2; ++ks2) {
            int row_a = w * 16 + ln;
            const float* sp = &sS[row_a][ks2 * 32 + quad * 8];
            float4 f0 = *(float4*)sp;
            float4 f1 = *((float4*)sp + 1);
            half8 pa = {(HALF)f0.x, (HALF)f0.y, (HALF)f0.z, (HALF)f0.w,
                        (HALF)f1.x, (HALF)f1.y, (HALF)f1.z, (HALF)f1.w};
#pragma unroll
            for (int t4 = 0; t4 < 4; ++t4) {
                half8 vb = *(half8*)&sVt[t4 * 16 + ln][ks2 * 32 + quad * 8];
                cacc[t4] = MFMA16(pa, vb, cacc[t4]);
            }
        }
        __syncthreads();
    }

    // ---- masked tiles: pure zero stores ----
    float4 z4 = {0.f, 0.f, 0.f, 0.f};
    for (int nt = nvt; nt < 64; ++nt) {
        int n0 = nt * 64;
#pragma unroll
        for (int s = 0; s < 4; ++s) {
            int row = s * 16 + (tid >> 4);
            int col = (tid & 15) * 4;
            *(float4*)(attn_base + (size_t)row * 4096 + n0 + col) = z4;
        }
    }

    // ---- ctx epilogue (into d_out's out-region; kernel 3 finishes) ----
    float* ctx_base = ctx_out + ((size_t)(b * 4096 + m0)) * 64;
#pragma unroll
    for (int t4 = 0; t4 < 4; ++t4) {
#pragma unroll
        for (int r = 0; r < 4; ++r) {
            ctx_base[(size_t)(w * 16 + quad * 4 + r) * 64 + t4 * 16 + ln] = cacc[t4][r];
        }
    }
}

// ---------------- kernel 3: out = ctx @ Wo + bo, in place ----------------
__global__ __launch_bounds__(256) void k_out(float* __restrict__ outg,
                                             const HALF* __restrict__ wto,
                                             const float* __restrict__ bo) {
    int bid = blockIdx.x;   // 512 blocks, 64 rows each
    size_t row0 = (size_t)bid * 64;
    int tid = threadIdx.x;
    int w = tid >> 6, lane = tid & 63, ln = lane & 15, quad = lane >> 4;

    __shared__ char smem[18432];
    HALF (*sA)[72] = (HALF(*)[72])smem;
    HALF (*sB)[72] = (HALF(*)[72])(smem + 9216);

    float* gbase = outg + row0 * 64;
#pragma unroll
    for (int s = 0; s < 4; ++s) {
        int flat = (s * 256 + tid) * 4;
        int r = flat >> 6, c = flat & 63;
        float4 v = *(const float4*)(gbase + flat);
        Cv4 cv; cv.h[0] = (HALF)v.x; cv.h[1] = (HALF)v.y;
        cv.h[2] = (HALF)v.z; cv.h[3] = (HALF)v.w;
        *(uint2*)&sA[r][c] = cv.u;
    }
#pragma unroll
    for (int s = 0; s < 2; ++s) {
        int flat = (s * 256 + tid) * 8;
        *(uint4*)&sB[flat >> 6][flat & 63] = *(const uint4*)(wto + flat);
    }
    __syncthreads();

    f32x4 z = {0.f, 0.f, 0.f, 0.f};
    f32x4 acc[4] = {z, z, z, z};
#pragma unroll
    for (int ks2 = 0; ks2 < 2; ++ks2) {
        half8 a = *(half8*)&sA[w * 16 + ln][ks2 * 32 + quad * 8];
#pragma unroll
        for (int t4 = 0; t4 < 4; ++t4) {
            half8 bf = *(half8*)&sB[t4 * 16 + ln][ks2 * 32 + quad * 8];
            acc[t4] = MFMA16(a, bf, acc[t4]);
        }
    }
#pragma unroll
    for (int t4 = 0; t4 < 4; ++t4) {
        float bov = bo[t4 * 16 + ln];
#pragma unroll
        for (int r = 0; r < 4; ++r) {
            gbase[(size_t)(w * 16 + quad * 4 + r) * 64 + t4 * 16 + ln] = acc[t4][r] + bov;
        }
    }
}

// ---------------- launch ----------------
extern "C" void kernel_launch(void* const* d_in, const int* in_sizes, int n_in,
                              void* d_out, int out_size, void* d_ws, size_t ws_size,
                              hipStream_t stream) {
    const float* qs = (const float*)d_in[0];
    const float* ks = (const float*)d_in[1];
    const float* vs = (const float*)d_in[2];
    const int* vlen = (const int*)d_in[3];
    const float* Wq = (const float*)d_in[4];
    const float* bq = (const float*)d_in[5];
    const float* Wk = (const float*)d_in[6];
    const float* bk = (const float*)d_in[7];
    const float* Wv = (const float*)d_in[8];
    const float* bv = (const float*)d_in[9];
    const float* Wo = (const float*)d_in[10];
    const float* bo = (const float*)d_in[11];

    float* out  = (float*)d_out;            // [8,4096,64]
    float* attn = out + 2097152;            // [8,4096,4096]

    char* wsb = (char*)d_ws;
    HALF*  wt  = (HALF*)(wsb + 0);          //  98304 B : W^T f16 (q,k,v)
    HALF*  wto = (HALF*)(wsb + 98304);      //   8192 B : Wo^T f16
    HALF*  qh  = (HALF*)(wsb + 131072);     //   4 MB   : q f16 [b][m][64]
    HALF*  kh  = (HALF*)(wsb + 4325376);    //   4 MB   : k f16 [b][n][64]
    HALF*  vth = (HALF*)(wsb + 8519680);    //   4 MB   : v^T f16 [b][dv][n]
    float* q2w = (float*)(wsb + 12713984);  // 128 KB
    float* k2w = (float*)(wsb + 12845056);  // 128 KB  (total ~12.4 MB)

    k_prep<<<208, 256, 0, stream>>>(Wq, Wk, Wv, Wo, wt, wto);
    k_proj<<<1536, 256, 0, stream>>>(qs, ks, vs, bq, bk, bv, wt, qh, kh, vth, q2w, k2w);
    k_attn<<<512, 256, 0, stream>>>(qh, kh, vth, q2w, k2w, vlen, attn, out);
    k_out<<<512, 256, 0, stream>>>(out, wto, bo);
}

// Round 3
// 688.060 us; speedup vs baseline: 1.1525x; 1.1525x over previous
//
#include <hip/hip_runtime.h>
#include <hip/hip_bf16.h>

// RBF-kernel attention, MI355X.  B=8, Q=K=4096, D=256, d=64.
// Outputs (concat fp32): out [8,4096,64] then attn [8,4096,4096].
// R3 = R2 with cvt_pkrtz type fix (__fp16 vector member in the pack union).
// R2: fold q2/k2 into exp arg (q2 cancels in normalization; mask via kc=-inf),
// diagonal batch swizzle for XCD balance, register-prefetch double buffering,
// launch_bounds(256,4), fused ctx@Wo+bo epilogue, pkrtz packing.

typedef _Float16 HALF;
typedef HALF half8 __attribute__((ext_vector_type(8)));
typedef __fp16 fp16x2 __attribute__((ext_vector_type(2)));
typedef float f32x4 __attribute__((ext_vector_type(4)));

#define MFMA16(a, b, c) __builtin_amdgcn_mfma_f32_16x16x32_f16((a), (b), (c), 0, 0, 0)

union Cv4 { HALF h[4]; uint2 u; };
union Cv8 { HALF h[8]; uint4 u; };
union PK8 { fp16x2 p2[4]; half8 v; };

// ---------------- kernel 0: W transposes -> f16 ----------------
__global__ __launch_bounds__(256) void k_prep(const float* __restrict__ Wq,
                                              const float* __restrict__ Wk,
                                              const float* __restrict__ Wv,
                                              const float* __restrict__ Wo,
                                              HALF* __restrict__ wt,
                                              HALF* __restrict__ wto) {
    int gid = blockIdx.x * 256 + threadIdx.x;   // 208*256 = 53248 exact
    if (gid < 49152) {
        int t = gid >> 14;
        int rem = gid & 16383;
        int n = rem >> 8, k = rem & 255;
        const float* W = (t == 0) ? Wq : ((t == 1) ? Wk : Wv);
        wt[gid] = (HALF)W[k * 64 + n];
    } else {
        int rem = gid - 49152;
        int n = rem >> 6, k = rem & 63;
        wto[rem] = (HALF)Wo[k * 64 + n];
    }
}

// ---------------- kernel 1: projections ----------------
// Emits q_h/k_h row-major f16, v transposed vt[b][dv][key] f16,
// kc[b][key] = -0.125*||k_row||^2 (bias included).
__global__ __launch_bounds__(256, 2) void k_proj(const float* __restrict__ qs,
                                                 const float* __restrict__ ks,
                                                 const float* __restrict__ vs,
                                                 const float* __restrict__ bq,
                                                 const float* __restrict__ bk,
                                                 const float* __restrict__ bv,
                                                 const HALF* __restrict__ wt,
                                                 HALF* __restrict__ qh,
                                                 HALF* __restrict__ kh,
                                                 HALF* __restrict__ vth,
                                                 float* __restrict__ kcw) {
    int bid = blockIdx.x;
    int t = bid >> 9;           // which projection
    int rem = bid & 511;
    int b = rem & 7, rt = rem >> 3;
    int m0 = rt * 64;
    const float* X    = (t == 0) ? qs : ((t == 1) ? ks : vs);
    const float* bias = (t == 0) ? bq : ((t == 1) ? bk : bv);

    __shared__ char smem[67584];
    HALF (*sW)[264]  = (HALF(*)[264])smem;             // 33792 B
    HALF (*sX)[264]  = (HALF(*)[264])(smem + 33792);   // 33792 B
    float (*sOut)[68] = (float(*)[68])(smem + 33792);  // overlaps sX

    int tid = threadIdx.x;
    int w = tid >> 6, lane = tid & 63, ln = lane & 15, quad = lane >> 4;

    const HALF* wsrc = wt + t * 16384;
#pragma unroll
    for (int s = 0; s < 8; ++s) {
        int flat = (s * 256 + tid) * 8;
        int r = flat >> 8, c = flat & 255;
        *(uint4*)&sW[r][c] = *(const uint4*)(wsrc + flat);
    }
    const float* xbase = X + ((size_t)(b * 4096 + m0)) * 256;
#pragma unroll
    for (int s = 0; s < 16; ++s) {
        int flat = (s * 256 + tid) * 4;
        int r = flat >> 8, c = flat & 255;
        float4 xv = *(const float4*)(xbase + flat);
        Cv4 cv; cv.h[0] = (HALF)xv.x; cv.h[1] = (HALF)xv.y;
        cv.h[2] = (HALF)xv.z; cv.h[3] = (HALF)xv.w;
        *(uint2*)&sX[r][c] = cv.u;
    }
    __syncthreads();

    f32x4 zero4 = {0.f, 0.f, 0.f, 0.f};
    f32x4 acc[4] = {zero4, zero4, zero4, zero4};
#pragma unroll
    for (int kb = 0; kb < 8; ++kb) {
        half8 a = *(half8*)&sX[w * 16 + ln][kb * 32 + quad * 8];
#pragma unroll
        for (int t4 = 0; t4 < 4; ++t4) {
            half8 bf = *(half8*)&sW[t4 * 16 + ln][kb * 32 + quad * 8];
            acc[t4] = MFMA16(a, bf, acc[t4]);
        }
    }
    __syncthreads();   // done reading sX; reuse as sOut

    float bias_v[4];
#pragma unroll
    for (int t4 = 0; t4 < 4; ++t4) bias_v[t4] = bias[t4 * 16 + ln];

    float rsq[4] = {0.f, 0.f, 0.f, 0.f};
#pragma unroll
    for (int t4 = 0; t4 < 4; ++t4) {
#pragma unroll
        for (int r = 0; r < 4; ++r) {
            float v = acc[t4][r] + bias_v[t4];
            rsq[r] += v * v;
            sOut[w * 16 + quad * 4 + r][t4 * 16 + ln] = v;
        }
    }
    if (t == 1) {
#pragma unroll
        for (int r = 0; r < 4; ++r) {
            float v = rsq[r];
#pragma unroll
            for (int off = 1; off < 16; off <<= 1) v += __shfl_xor(v, off);
            if (ln == 0) kcw[b * 4096 + m0 + w * 16 + quad * 4 + r] = -0.125f * v;
        }
    }
    __syncthreads();

    if (t < 2) {
        HALF* dst = ((t == 0) ? qh : kh) + ((size_t)(b * 4096 + m0)) * 64;
#pragma unroll
        for (int s = 0; s < 4; ++s) {
            int flat = (s * 256 + tid) * 4;
            int r = flat >> 6, c = flat & 63;
            float4 v = *(float4*)&sOut[r][c];
            Cv4 cv; cv.h[0] = (HALF)v.x; cv.h[1] = (HALF)v.y;
            cv.h[2] = (HALF)v.z; cv.h[3] = (HALF)v.w;
            *(uint2*)(dst + flat) = cv.u;
        }
    } else {
        HALF* dst = vth + (size_t)b * 64 * 4096 + m0;
#pragma unroll
        for (int s = 0; s < 2; ++s) {
            int dv = s * 32 + (tid >> 3);
            int kc = (tid & 7) * 8;
            Cv8 cv;
#pragma unroll
            for (int i = 0; i < 8; ++i) cv.h[i] = (HALF)sOut[kc + i][dv];
            *(uint4*)(dst + (size_t)dv * 4096 + kc) = cv.u;
        }
    }
}

// ---------------- kernel 2: two-pass RBF attention + fused out ----------------
__global__ __launch_bounds__(256, 4) void k_attn(const HALF* __restrict__ qh,
                                                 const HALF* __restrict__ kh,
                                                 const HALF* __restrict__ vth,
                                                 const float* __restrict__ kcw,
                                                 const int* __restrict__ vlen,
                                                 const HALF* __restrict__ wto,
                                                 const float* __restrict__ bo,
                                                 float* __restrict__ attn_out,
                                                 float* __restrict__ out) {
    int bid = blockIdx.x;
    int qt = bid >> 3;
    int b = (bid + qt) & 7;       // diagonal swizzle: balances valid_lens across XCDs
    int m0 = qt * 64;
    int tid = threadIdx.x;
    int w = tid >> 6, lane = tid & 63, ln = lane & 15, quad = lane >> 4;
    int valid = vlen[b];

    __shared__ char smem[36352];
    HALF (*sK)[72]  = (HALF(*)[72])smem;               //  9216 B
    HALF (*sVt)[72] = (HALF(*)[72])(smem + 9216);      //  9216 B
    float (*sS)[68] = (float(*)[68])(smem + 18432);    // 17408 B
    HALF (*sQ)[72]  = (HALF(*)[72])(smem + 18432);     // overlaps sS (start only)
    HALF (*sWo)[72] = (HALF(*)[72])smem;               // overlaps sK (epilogue only)
    float* sKC = (float*)(smem + 35840);
    float* sRS = (float*)(smem + 36096);

    // stage q tile
    const HALF* qbase = qh + ((size_t)(b * 4096 + m0)) * 64;
    { int f0 = tid * 8;         *(uint4*)&sQ[f0 >> 6][f0 & 63] = *(const uint4*)(qbase + f0);
      int f1 = (256 + tid) * 8; *(uint4*)&sQ[f1 >> 6][f1 & 63] = *(const uint4*)(qbase + f1); }
    __syncthreads();
    half8 qa0, qa1;
    { int row = w * 16 + ln, k0 = quad * 8;
      qa0 = *(half8*)&sQ[row][k0];
      qa1 = *(half8*)&sQ[row][32 + k0]; }
    __syncthreads();   // sQ region becomes sS

    int nvt = (valid + 63) >> 6;
    const HALF* kbb = kh + (size_t)b * 4096 * 64;
    const HALF* vtb = vth + (size_t)b * 64 * 4096;
    const float* kcb = kcw + b * 4096;
    const float NEG_INF = -__builtin_inff();

    // ---- pass A: rowsums (register-prefetched K tiles) ----
    uint4 kr0, kr1; float kcr = 0.f;
    kr0 = *(const uint4*)(kbb + tid * 8);
    kr1 = *(const uint4*)(kbb + (256 + tid) * 8);
    if (tid < 64) kcr = kcb[tid];

    float rs[4] = {0.f, 0.f, 0.f, 0.f};
    for (int nt = 0; nt < nvt; ++nt) {
        int n0 = nt * 64;
        { int f0 = tid * 8;         *(uint4*)&sK[f0 >> 6][f0 & 63] = kr0;
          int f1 = (256 + tid) * 8; *(uint4*)&sK[f1 >> 6][f1 & 63] = kr1; }
        if (tid < 64) sKC[tid] = (n0 + tid < valid) ? kcr : NEG_INF;
        __syncthreads();
        if (nt + 1 < nvt) {
            const HALF* src = kbb + (size_t)(nt + 1) * 4096;
            kr0 = *(const uint4*)(src + tid * 8);
            kr1 = *(const uint4*)(src + (256 + tid) * 8);
            if (tid < 64) kcr = kcb[n0 + 64 + tid];
        }
#pragma unroll
        for (int t4 = 0; t4 < 4; ++t4) {
            f32x4 acc = {0.f, 0.f, 0.f, 0.f};
            half8 b0 = *(half8*)&sK[t4 * 16 + ln][quad * 8];
            half8 b1 = *(half8*)&sK[t4 * 16 + ln][32 + quad * 8];
            acc = MFMA16(qa0, b0, acc);
            acc = MFMA16(qa1, b1, acc);
            float kcv = sKC[t4 * 16 + ln];
#pragma unroll
            for (int r = 0; r < 4; ++r)
                rs[r] += __expf(fmaf(acc[r], 0.25f, kcv));
        }
        __syncthreads();
    }

#pragma unroll
    for (int r = 0; r < 4; ++r) {
        float v = rs[r];
#pragma unroll
        for (int off = 1; off < 16; off <<= 1) v += __shfl_xor(v, off);
        rs[r] = v;
    }
    if (ln == 0) {
#pragma unroll
        for (int r = 0; r < 4; ++r) sRS[w * 16 + quad * 4 + r] = rs[r];
    }
    __syncthreads();
    if (tid < 64) sRS[tid] = 1.0f / sRS[tid];
    __syncthreads();
    float inv_r[4];
#pragma unroll
    for (int r = 0; r < 4; ++r) inv_r[r] = sRS[w * 16 + quad * 4 + r];

    // ---- pass B: recompute, normalize, write attn, PV ----
    f32x4 cz = {0.f, 0.f, 0.f, 0.f};
    f32x4 cacc[4] = {cz, cz, cz, cz};
    float* attn_base = attn_out + ((size_t)(b * 4096 + m0)) * 4096;

    uint4 vr0, vr1;
    kr0 = *(const uint4*)(kbb + tid * 8);
    kr1 = *(const uint4*)(kbb + (256 + tid) * 8);
    { int f0 = tid * 8, f1 = (256 + tid) * 8;
      vr0 = *(const uint4*)(vtb + (size_t)(f0 >> 6) * 4096 + (f0 & 63));
      vr1 = *(const uint4*)(vtb + (size_t)(f1 >> 6) * 4096 + (f1 & 63)); }
    if (tid < 64) kcr = kcb[tid];

    for (int nt = 0; nt < nvt; ++nt) {
        int n0 = nt * 64;
        { int f0 = tid * 8, f1 = (256 + tid) * 8;
          *(uint4*)&sK[f0 >> 6][f0 & 63] = kr0;
          *(uint4*)&sK[f1 >> 6][f1 & 63] = kr1;
          *(uint4*)&sVt[f0 >> 6][f0 & 63] = vr0;
          *(uint4*)&sVt[f1 >> 6][f1 & 63] = vr1; }
        if (tid < 64) sKC[tid] = (n0 + tid < valid) ? kcr : NEG_INF;
        __syncthreads();
        if (nt + 1 < nvt) {
            const HALF* ksrc = kbb + (size_t)(nt + 1) * 4096;
            int f0 = tid * 8, f1 = (256 + tid) * 8;
            kr0 = *(const uint4*)(ksrc + f0);
            kr1 = *(const uint4*)(ksrc + f1);
            vr0 = *(const uint4*)(vtb + (size_t)(f0 >> 6) * 4096 + n0 + 64 + (f0 & 63));
            vr1 = *(const uint4*)(vtb + (size_t)(f1 >> 6) * 4096 + n0 + 64 + (f1 & 63));
            if (tid < 64) kcr = kcb[n0 + 64 + tid];
        }
#pragma unroll
        for (int t4 = 0; t4 < 4; ++t4) {
            f32x4 acc = {0.f, 0.f, 0.f, 0.f};
            half8 b0 = *(half8*)&sK[t4 * 16 + ln][quad * 8];
            half8 b1 = *(half8*)&sK[t4 * 16 + ln][32 + quad * 8];
            acc = MFMA16(qa0, b0, acc);
            acc = MFMA16(qa1, b1, acc);
            int col = t4 * 16 + ln;
            float kcv = sKC[col];
#pragma unroll
            for (int r = 0; r < 4; ++r) {
                int row = w * 16 + quad * 4 + r;
                sS[row][col] = __expf(fmaf(acc[r], 0.25f, kcv)) * inv_r[r];
            }
        }
        __syncthreads();
        // coalesced attn tile store (256B segments per row)
#pragma unroll
        for (int s = 0; s < 4; ++s) {
            int row = s * 16 + (tid >> 4);
            int col = (tid & 15) * 4;
            *(float4*)(attn_base + (size_t)row * 4096 + n0 + col) = *(float4*)&sS[row][col];
        }
        // PV
#pragma unroll
        for (int ks2 = 0; ks2 < 2; ++ks2) {
            const float* sp = &sS[w * 16 + ln][ks2 * 32 + quad * 8];
            float4 f0 = *(float4*)sp;
            float4 f1 = *((float4*)sp + 1);
            PK8 pk;
            pk.p2[0] = __builtin_amdgcn_cvt_pkrtz(f0.x, f0.y);
            pk.p2[1] = __builtin_amdgcn_cvt_pkrtz(f0.z, f0.w);
            pk.p2[2] = __builtin_amdgcn_cvt_pkrtz(f1.x, f1.y);
            pk.p2[3] = __builtin_amdgcn_cvt_pkrtz(f1.z, f1.w);
            half8 pa = pk.v;
#pragma unroll
            for (int t4 = 0; t4 < 4; ++t4) {
                half8 vb = *(half8*)&sVt[t4 * 16 + ln][ks2 * 32 + quad * 8];
                cacc[t4] = MFMA16(pa, vb, cacc[t4]);
            }
        }
        __syncthreads();
    }

    // ---- masked tiles: pure zero stores ----
    float4 z4 = {0.f, 0.f, 0.f, 0.f};
    for (int nt = nvt; nt < 64; ++nt) {
        int n0 = nt * 64;
#pragma unroll
        for (int s = 0; s < 4; ++s) {
            int row = s * 16 + (tid >> 4);
            int col = (tid & 15) * 4;
            *(float4*)(attn_base + (size_t)row * 4096 + n0 + col) = z4;
        }
    }

    // ---- fused epilogue: out = ctx @ Wo + bo ----
#pragma unroll
    for (int t4 = 0; t4 < 4; ++t4) {
#pragma unroll
        for (int r = 0; r < 4; ++r)
            sS[w * 16 + quad * 4 + r][t4 * 16 + ln] = cacc[t4][r];
    }
    { int f0 = tid * 8;         *(uint4*)&sWo[f0 >> 6][f0 & 63] = *(const uint4*)(wto + f0);
      int f1 = (256 + tid) * 8; *(uint4*)&sWo[f1 >> 6][f1 & 63] = *(const uint4*)(wto + f1); }
    __syncthreads();

    f32x4 oacc[4] = {cz, cz, cz, cz};
#pragma unroll
    for (int ks2 = 0; ks2 < 2; ++ks2) {
        const float* sp = &sS[w * 16 + ln][ks2 * 32 + quad * 8];
        float4 f0 = *(float4*)sp;
        float4 f1 = *((float4*)sp + 1);
        PK8 pk;
        pk.p2[0] = __builtin_amdgcn_cvt_pkrtz(f0.x, f0.y);
        pk.p2[1] = __builtin_amdgcn_cvt_pkrtz(f0.z, f0.w);
        pk.p2[2] = __builtin_amdgcn_cvt_pkrtz(f1.x, f1.y);
        pk.p2[3] = __builtin_amdgcn_cvt_pkrtz(f1.z, f1.w);
        half8 a = pk.v;
#pragma unroll
        for (int t4 = 0; t4 < 4; ++t4) {
            half8 bf = *(half8*)&sWo[t4 * 16 + ln][ks2 * 32 + quad * 8];
            oacc[t4] = MFMA16(a, bf, oacc[t4]);
        }
    }
    float* obase = out + ((size_t)(b * 4096 + m0)) * 64;
#pragma unroll
    for (int t4 = 0; t4 < 4; ++t4) {
        float bov = bo[t4 * 16 + ln];
#pragma unroll
        for (int r = 0; r < 4; ++r)
            obase[(size_t)(w * 16 + quad * 4 + r) * 64 + t4 * 16 + ln] = oacc[t4][r] + bov;
    }
}

// ---------------- launch ----------------
extern "C" void kernel_launch(void* const* d_in, const int* in_sizes, int n_in,
                              void* d_out, int out_size, void* d_ws, size_t ws_size,
                              hipStream_t stream) {
    const float* qs = (const float*)d_in[0];
    const float* ks = (const float*)d_in[1];
    const float* vs = (const float*)d_in[2];
    const int* vlen = (const int*)d_in[3];
    const float* Wq = (const float*)d_in[4];
    const float* bq = (const float*)d_in[5];
    const float* Wk = (const float*)d_in[6];
    const float* bk = (const float*)d_in[7];
    const float* Wv = (const float*)d_in[8];
    const float* bv = (const float*)d_in[9];
    const float* Wo = (const float*)d_in[10];
    const float* bo = (const float*)d_in[11];

    float* out  = (float*)d_out;            // [8,4096,64]
    float* attn = out + 2097152;            // [8,4096,4096]

    char* wsb = (char*)d_ws;
    HALF*  wt  = (HALF*)(wsb + 0);          //  98304 B : W^T f16 (q,k,v)
    HALF*  wto = (HALF*)(wsb + 98304);      //   8192 B : Wo^T f16
    HALF*  qh  = (HALF*)(wsb + 131072);     //   4 MB   : q f16 [b][m][64]
    HALF*  kh  = (HALF*)(wsb + 4325376);    //   4 MB   : k f16 [b][n][64]
    HALF*  vth = (HALF*)(wsb + 8519680);    //   4 MB   : v^T f16 [b][dv][n]
    float* kcw = (float*)(wsb + 12713984);  // 128 KB   : -0.125*||k||^2

    k_prep<<<208, 256, 0, stream>>>(Wq, Wk, Wv, Wo, wt, wto);
    k_proj<<<1536, 256, 0, stream>>>(qs, ks, vs, bq, bk, bv, wt, qh, kh, vth, kcw);
    k_attn<<<512, 256, 0, stream>>>(qh, kh, vth, kcw, vlen, wto, bo, attn, out);
}